// Round 1
// baseline (1518.446 us; speedup 1.0000x reference)
//
#include <hip/hip_runtime.h>

// ---------------- kernels ----------------

__global__ __launch_bounds__(256) void k_deg(const int* __restrict__ row,
                                             int* __restrict__ deg, int E) {
    int i = blockIdx.x * 256 + threadIdx.x;
    if (i < E) atomicAdd(&deg[row[i]], 1);
}

// in-place: reads int count, writes float 1/sqrt(count+1)
__global__ __launch_bounds__(256) void k_invsqrt(float* __restrict__ d, int N) {
    int i = blockIdx.x * 256 + threadIdx.x;
    if (i < N) {
        int c = ((const int*)d)[i];
        d[i] = 1.0f / sqrtf((float)(c + 1));
    }
}

__global__ __launch_bounds__(256) void k_norm(const int* __restrict__ row,
                                              const int* __restrict__ col,
                                              const float* __restrict__ invs,
                                              float* __restrict__ norm, int E) {
    int i = blockIdx.x * 256 + threadIdx.x;
    if (i < E) norm[i] = invs[row[i]] * invs[col[i]];
}

// x[N,128] @ W[128,64] -> out[N,64]; 4 rows per 256-thread block
__global__ __launch_bounds__(256) void k_gemm0(const float* __restrict__ x,
                                               const float* __restrict__ W,
                                               float* __restrict__ out, int N) {
    __shared__ float sW[128 * 64];
    for (int i = threadIdx.x; i < 128 * 64; i += 256) sW[i] = W[i];
    __syncthreads();
    int row = blockIdx.x * 4 + (threadIdx.x >> 6);
    int c = threadIdx.x & 63;
    if (row >= N) return;
    const float4* xr = (const float4*)(x + (size_t)row * 128);
    float acc = 0.f;
#pragma unroll
    for (int k4 = 0; k4 < 32; ++k4) {
        float4 xv = xr[k4];
        int k = k4 * 4;
        acc = fmaf(xv.x, sW[(k + 0) * 64 + c], acc);
        acc = fmaf(xv.y, sW[(k + 1) * 64 + c], acc);
        acc = fmaf(xv.z, sW[(k + 2) * 64 + c], acc);
        acc = fmaf(xv.w, sW[(k + 3) * 64 + c], acc);
    }
    out[(size_t)row * 64 + c] = acc;
}

// h[N,64] @ W[64,32] -> out[N,32]; 8 rows per block
__global__ __launch_bounds__(256) void k_gemm1(const float* __restrict__ h,
                                               const float* __restrict__ W,
                                               float* __restrict__ out, int N) {
    __shared__ float sW[64 * 32];
    for (int i = threadIdx.x; i < 64 * 32; i += 256) sW[i] = W[i];
    __syncthreads();
    int row = blockIdx.x * 8 + (threadIdx.x >> 5);
    int c = threadIdx.x & 31;
    if (row >= N) return;
    const float4* hr = (const float4*)(h + (size_t)row * 64);
    float acc = 0.f;
#pragma unroll
    for (int k4 = 0; k4 < 16; ++k4) {
        float4 hv = hr[k4];
        int k = k4 * 4;
        acc = fmaf(hv.x, sW[(k + 0) * 32 + c], acc);
        acc = fmaf(hv.y, sW[(k + 1) * 32 + c], acc);
        acc = fmaf(hv.z, sW[(k + 2) * 32 + c], acc);
        acc = fmaf(hv.w, sW[(k + 3) * 32 + c], acc);
    }
    out[(size_t)row * 32 + c] = acc;
}

// one thread per (edge, feature); 64 feats: lanes of a wave share one edge
__global__ __launch_bounds__(256) void k_agg64(const int* __restrict__ row,
                                               const int* __restrict__ col,
                                               const float* __restrict__ norm,
                                               const float* __restrict__ src,
                                               float* __restrict__ dst,
                                               unsigned total) {
    unsigned idx = blockIdx.x * 256u + threadIdx.x;
    if (idx >= total) return;
    unsigned e = idx >> 6, j = idx & 63u;
    float v = norm[e] * src[(size_t)col[e] * 64 + j];
    atomicAdd(&dst[(size_t)row[e] * 64 + j], v);
}

__global__ __launch_bounds__(256) void k_agg32(const int* __restrict__ row,
                                               const int* __restrict__ col,
                                               const float* __restrict__ norm,
                                               const float* __restrict__ src,
                                               float* __restrict__ dst,
                                               unsigned total) {
    unsigned idx = blockIdx.x * 256u + threadIdx.x;
    if (idx >= total) return;
    unsigned e = idx >> 5, j = idx & 31u;
    float v = norm[e] * src[(size_t)col[e] * 32 + j];
    atomicAdd(&dst[(size_t)row[e] * 32 + j], v);
}

// h0 = relu(agg + invs^2 * hW + b)  (self-loop term folded in), in place in agg
__global__ __launch_bounds__(256) void k_relu0(const float* __restrict__ hW,
                                               float* __restrict__ agg,
                                               const float* __restrict__ invs,
                                               const float* __restrict__ b,
                                               unsigned total) {
    unsigned idx = blockIdx.x * 256u + threadIdx.x;
    if (idx >= total) return;
    unsigned i = idx >> 6, j = idx & 63u;
    float is = invs[i];
    float v = agg[idx] + is * is * hW[idx] + b[j];
    agg[idx] = v > 0.f ? v : 0.f;
}

// layer-1 relu fused with graph mean-pool accumulation (h1 never stored)
__global__ __launch_bounds__(256) void k_relu1_pool(const float* __restrict__ hW,
                                                    const float* __restrict__ agg,
                                                    const float* __restrict__ invs,
                                                    const float* __restrict__ b,
                                                    const int* __restrict__ gidx,
                                                    float* __restrict__ pooled,
                                                    unsigned total) {
    unsigned idx = blockIdx.x * 256u + threadIdx.x;
    if (idx >= total) return;
    unsigned i = idx >> 5, j = idx & 31u;
    float is = invs[i];
    float v = agg[idx] + is * is * hW[idx] + b[j];
    v = v > 0.f ? v : 0.f;
    atomicAdd(&pooled[(size_t)gidx[i] * 32 + j], v);
}

__global__ __launch_bounds__(256) void k_cnt(const int* __restrict__ gidx,
                                             int* __restrict__ cnt, int N) {
    int i = blockIdx.x * 256 + threadIdx.x;
    if (i < N) atomicAdd(&cnt[gidx[i]], 1);
}

// out[g,c] = (pooled[g,:]/max(cnt,1)) @ Wd[:,c] + bd[c]
__global__ __launch_bounds__(256) void k_final(const float* __restrict__ pooled,
                                               const int* __restrict__ cnt,
                                               const float* __restrict__ Wd,
                                               const float* __restrict__ bd,
                                               float* __restrict__ out, int total) {
    int idx = blockIdx.x * 256 + threadIdx.x;
    if (idx >= total) return;
    int g = idx >> 4, c = idx & 15;
    float denom = fmaxf((float)cnt[g], 1.0f);
    float acc = 0.f;
#pragma unroll
    for (int j = 0; j < 32; ++j)
        acc = fmaf(pooled[g * 32 + j], Wd[j * 16 + c], acc);
    out[idx] = acc / denom + bd[c];
}

// ---------------- launch ----------------

extern "C" void kernel_launch(void* const* d_in, const int* in_sizes, int n_in,
                              void* d_out, int out_size, void* d_ws, size_t ws_size,
                              hipStream_t stream) {
    const float* x   = (const float*)d_in[0];
    const int*  erow = (const int*)d_in[1];              // edge targets
    const float* W0  = (const float*)d_in[3];
    const float* b0  = (const float*)d_in[4];
    const float* W1  = (const float*)d_in[5];
    const float* b1  = (const float*)d_in[6];
    const float* Wd  = (const float*)d_in[7];
    const float* bd  = (const float*)d_in[8];
    const int*  gidx = (const int*)d_in[2];
    float* out = (float*)d_out;

    const int E = in_sizes[1] / 2;
    const int* ecol = erow + E;                          // edge sources
    const int N = in_sizes[2];
    const int G = out_size / 16;

    char* ws = (char*)d_ws;
    size_t oInvs = 0;                                    // N floats (also deg ints)
    size_t oNorm = oInvs + (size_t)N * 4;                // E floats
    size_t oA    = oNorm + (size_t)E * 4;                // N*64 floats (hW0; later hW1|agg1)
    size_t oB    = oA + (size_t)N * 256;                 // N*64 floats (agg0 -> h0)
    size_t oP    = oB + (size_t)N * 256;                 // G*32 floats pooled
    size_t oCnt  = oP + (size_t)G * 128;                 // G ints

    float* invs  = (float*)(ws + oInvs);
    float* normp = (float*)(ws + oNorm);
    float* bufA  = (float*)(ws + oA);
    float* bufB  = (float*)(ws + oB);
    float* pooled = (float*)(ws + oP);
    int*   cnt   = (int*)(ws + oCnt);

    float* hW1  = bufA;                                  // N*32
    float* agg1 = bufA + (size_t)N * 32;                 // N*32

    // zero-init accumulators (ws is poisoned before every launch)
    hipMemsetAsync(ws + oInvs, 0, (size_t)N * 4, stream);
    hipMemsetAsync(ws + oB, 0, (size_t)N * 256, stream);
    hipMemsetAsync(ws + oP, 0, (size_t)G * 128 + (size_t)G * 4, stream);

    // degree + norms
    k_deg<<<(E + 255) / 256, 256, 0, stream>>>(erow, (int*)invs, E);
    k_invsqrt<<<(N + 255) / 256, 256, 0, stream>>>(invs, N);
    k_norm<<<(E + 255) / 256, 256, 0, stream>>>(erow, ecol, invs, normp, E);

    // layer 0: project then aggregate
    k_gemm0<<<(N + 3) / 4, 256, 0, stream>>>(x, W0, bufA, N);
    {
        unsigned total = (unsigned)E * 64u;
        k_agg64<<<(total + 255) / 256, 256, 0, stream>>>(erow, ecol, normp, bufA, bufB, total);
    }
    k_relu0<<<((unsigned)N * 64u + 255) / 256, 256, 0, stream>>>(bufA, bufB, invs, b0,
                                                                 (unsigned)N * 64u);

    // layer 1
    k_gemm1<<<(N + 7) / 8, 256, 0, stream>>>(bufB, W1, hW1, N);
    hipMemsetAsync((void*)agg1, 0, (size_t)N * 128, stream);
    {
        unsigned total = (unsigned)E * 32u;
        k_agg32<<<(total + 255) / 256, 256, 0, stream>>>(erow, ecol, normp, hW1, agg1, total);
    }
    k_relu1_pool<<<((unsigned)N * 32u + 255) / 256, 256, 0, stream>>>(
        hW1, agg1, invs, b1, gidx, pooled, (unsigned)N * 32u);
    k_cnt<<<(N + 255) / 256, 256, 0, stream>>>(gidx, cnt, N);

    // dense head
    k_final<<<(G * 16 + 255) / 256, 256, 0, stream>>>(pooled, cnt, Wd, bd, out, G * 16);
}

// Round 2
// 1042.907 us; speedup vs baseline: 1.4560x; 1.4560x over previous
//
#include <hip/hip_runtime.h>

// ---------------- degree / norm ----------------

__global__ __launch_bounds__(256) void k_deg(const int* __restrict__ row,
                                             int* __restrict__ deg, int E) {
    int i = blockIdx.x * 256 + threadIdx.x;
    if (i < E) atomicAdd(&deg[row[i]], 1);
}

__global__ __launch_bounds__(256) void k_invsqrt(const int* __restrict__ deg,
                                                 float* __restrict__ invs, int N) {
    int i = blockIdx.x * 256 + threadIdx.x;
    if (i < N) invs[i] = rsqrtf((float)(deg[i] + 1));
}

// ---------------- CSR build: scan + scatter ----------------

__global__ __launch_bounds__(256) void k_bsum(const int* __restrict__ deg,
                                              int* __restrict__ bsum, int N) {
    __shared__ int sd[256];
    int t = threadIdx.x;
    int i = blockIdx.x * 256 + t;
    sd[t] = (i < N) ? deg[i] : 0;
    __syncthreads();
    for (int d = 128; d > 0; d >>= 1) {
        if (t < d) sd[t] += sd[t + d];
        __syncthreads();
    }
    if (t == 0) bsum[blockIdx.x] = sd[0];
}

// exclusive scan of bsum in place (nb <= 1024)
__global__ __launch_bounds__(1024) void k_scan_bsums(int* __restrict__ bsum, int nb) {
    __shared__ int sd[1024];
    int t = threadIdx.x;
    int v = (t < nb) ? bsum[t] : 0;
    sd[t] = v;
    __syncthreads();
    for (int d = 1; d < 1024; d <<= 1) {
        int add = (t >= d) ? sd[t - d] : 0;
        __syncthreads();
        sd[t] += add;
        __syncthreads();
    }
    if (t < nb) bsum[t] = sd[t] - v;   // exclusive
}

__global__ __launch_bounds__(256) void k_scan_final(const int* __restrict__ deg,
                                                    const int* __restrict__ bsum,
                                                    int* __restrict__ off,
                                                    int* __restrict__ cursor,
                                                    int N, int E) {
    __shared__ int sd[256];
    int t = threadIdx.x;
    int i = blockIdx.x * 256 + t;
    int v = (i < N) ? deg[i] : 0;
    sd[t] = v;
    __syncthreads();
    for (int d = 1; d < 256; d <<= 1) {
        int add = (t >= d) ? sd[t - d] : 0;
        __syncthreads();
        sd[t] += add;
        __syncthreads();
    }
    if (i < N) {
        int ex = bsum[blockIdx.x] + sd[t] - v;
        off[i] = ex;
        cursor[i] = ex;
    }
    if (i == 0) off[N] = E;
}

__global__ __launch_bounds__(256) void k_scatter(const int* __restrict__ row,
                                                 const int* __restrict__ col,
                                                 int* __restrict__ cursor,
                                                 int* __restrict__ scol, int E) {
    int i = blockIdx.x * 256 + threadIdx.x;
    if (i < E) {
        int pos = atomicAdd(&cursor[row[i]], 1);
        scol[pos] = col[i];
    }
}

// ---------------- projections (store invs[row]-scaled) ----------------

// x[N,128] @ W[128,64], scaled: out[r,:] = invs[r] * (x[r]@W)
__global__ __launch_bounds__(256) void k_gemm0(const float* __restrict__ x,
                                               const float* __restrict__ W,
                                               const float* __restrict__ invs,
                                               float* __restrict__ out, int N) {
    __shared__ float sW[128 * 64];
    for (int i = threadIdx.x; i < 128 * 64; i += 256) sW[i] = W[i];
    __syncthreads();
    int row = blockIdx.x * 4 + (threadIdx.x >> 6);
    int c = threadIdx.x & 63;
    if (row >= N) return;
    const float4* xr = (const float4*)(x + (size_t)row * 128);
    float acc = 0.f;
#pragma unroll
    for (int k4 = 0; k4 < 32; ++k4) {
        float4 xv = xr[k4];
        int k = k4 * 4;
        acc = fmaf(xv.x, sW[(k + 0) * 64 + c], acc);
        acc = fmaf(xv.y, sW[(k + 1) * 64 + c], acc);
        acc = fmaf(xv.z, sW[(k + 2) * 64 + c], acc);
        acc = fmaf(xv.w, sW[(k + 3) * 64 + c], acc);
    }
    out[(size_t)row * 64 + c] = invs[row] * acc;
}

// h[N,64] @ W[64,32], scaled
__global__ __launch_bounds__(256) void k_gemm1(const float* __restrict__ h,
                                               const float* __restrict__ W,
                                               const float* __restrict__ invs,
                                               float* __restrict__ out, int N) {
    __shared__ float sW[64 * 32];
    for (int i = threadIdx.x; i < 64 * 32; i += 256) sW[i] = W[i];
    __syncthreads();
    int row = blockIdx.x * 8 + (threadIdx.x >> 5);
    int c = threadIdx.x & 31;
    if (row >= N) return;
    const float4* hr = (const float4*)(h + (size_t)row * 64);
    float acc = 0.f;
#pragma unroll
    for (int k4 = 0; k4 < 16; ++k4) {
        float4 hv = hr[k4];
        int k = k4 * 4;
        acc = fmaf(hv.x, sW[(k + 0) * 32 + c], acc);
        acc = fmaf(hv.y, sW[(k + 1) * 32 + c], acc);
        acc = fmaf(hv.z, sW[(k + 2) * 32 + c], acc);
        acc = fmaf(hv.w, sW[(k + 3) * 32 + c], acc);
    }
    out[(size_t)row * 32 + c] = invs[row] * acc;
}

// ---------------- CSR gather-aggregate ----------------

// block per node, 4 waves split edges, lanes = 64 features.
// hWs is invs-prescaled; out = relu(invs[i]*(sum_neighbors + self) + b)
__global__ __launch_bounds__(256) void k_csr_agg64(const int* __restrict__ scol,
                                                   const int* __restrict__ off,
                                                   const float* __restrict__ invs,
                                                   const float* __restrict__ hWs,
                                                   const float* __restrict__ bias,
                                                   float* __restrict__ h0, int N) {
    int i = blockIdx.x;
    int lane = threadIdx.x & 63, w = threadIdx.x >> 6;
    int s = off[i], e = off[i + 1];
    float a0 = 0.f, a1 = 0.f;
    int k = s + w;
    for (; k + 4 < e; k += 8) {
        int c0 = scol[k], c1 = scol[k + 4];
        a0 += hWs[(size_t)c0 * 64 + lane];
        a1 += hWs[(size_t)c1 * 64 + lane];
    }
    if (k < e) a0 += hWs[(size_t)scol[k] * 64 + lane];
    __shared__ float red[4][64];
    red[w][lane] = a0 + a1;
    __syncthreads();
    if (threadIdx.x < 64) {
        float v = red[0][lane] + red[1][lane] + red[2][lane] + red[3][lane];
        v = invs[i] * (v + hWs[(size_t)i * 64 + lane]) + bias[lane];
        h0[(size_t)i * 64 + lane] = v > 0.f ? v : 0.f;
    }
}

// block per node, 8 slices of 32 lanes; fused relu + mean-pool accumulate
__global__ __launch_bounds__(256) void k_csr_agg32_pool(const int* __restrict__ scol,
                                                        const int* __restrict__ off,
                                                        const float* __restrict__ invs,
                                                        const float* __restrict__ hWs,
                                                        const float* __restrict__ bias,
                                                        const int* __restrict__ gidx,
                                                        float* __restrict__ pooled,
                                                        int N) {
    int i = blockIdx.x;
    int lane = threadIdx.x & 31, w = threadIdx.x >> 5;
    int s = off[i], e = off[i + 1];
    float a0 = 0.f, a1 = 0.f;
    int k = s + w;
    for (; k + 8 < e; k += 16) {
        int c0 = scol[k], c1 = scol[k + 8];
        a0 += hWs[(size_t)c0 * 32 + lane];
        a1 += hWs[(size_t)c1 * 32 + lane];
    }
    if (k < e) a0 += hWs[(size_t)scol[k] * 32 + lane];
    __shared__ float red[8][32];
    red[w][lane] = a0 + a1;
    __syncthreads();
    if (threadIdx.x < 32) {
        float v = 0.f;
#pragma unroll
        for (int q = 0; q < 8; ++q) v += red[q][lane];
        v = invs[i] * (v + hWs[(size_t)i * 32 + lane]) + bias[lane];
        v = v > 0.f ? v : 0.f;
        atomicAdd(&pooled[(size_t)gidx[i] * 32 + lane], v);
    }
}

__global__ __launch_bounds__(256) void k_cnt(const int* __restrict__ gidx,
                                             int* __restrict__ cnt, int N) {
    int i = blockIdx.x * 256 + threadIdx.x;
    if (i < N) atomicAdd(&cnt[gidx[i]], 1);
}

__global__ __launch_bounds__(256) void k_final(const float* __restrict__ pooled,
                                               const int* __restrict__ cnt,
                                               const float* __restrict__ Wd,
                                               const float* __restrict__ bd,
                                               float* __restrict__ out, int total) {
    int idx = blockIdx.x * 256 + threadIdx.x;
    if (idx >= total) return;
    int g = idx >> 4, c = idx & 15;
    float denom = fmaxf((float)cnt[g], 1.0f);
    float acc = 0.f;
#pragma unroll
    for (int j = 0; j < 32; ++j)
        acc = fmaf(pooled[g * 32 + j], Wd[j * 16 + c], acc);
    out[idx] = acc / denom + bd[c];
}

// ---------------- launch ----------------

extern "C" void kernel_launch(void* const* d_in, const int* in_sizes, int n_in,
                              void* d_out, int out_size, void* d_ws, size_t ws_size,
                              hipStream_t stream) {
    const float* x   = (const float*)d_in[0];
    const int*  erow = (const int*)d_in[1];              // edge targets
    const int*  gidx = (const int*)d_in[2];
    const float* W0  = (const float*)d_in[3];
    const float* b0  = (const float*)d_in[4];
    const float* W1  = (const float*)d_in[5];
    const float* b1  = (const float*)d_in[6];
    const float* Wd  = (const float*)d_in[7];
    const float* bd  = (const float*)d_in[8];
    float* out = (float*)d_out;

    const int E = in_sizes[1] / 2;
    const int* ecol = erow + E;                          // edge sources
    const int N = in_sizes[2];
    const int G = out_size / 16;
    const int nb = (N + 255) / 256;

    char* ws = (char*)d_ws;
    size_t oInvs = 0;                                    // N floats
    size_t oOff  = oInvs + (size_t)N * 4;                // (N+8) ints
    size_t oBsum = oOff + (size_t)(N + 8) * 4;           // 1024 ints
    size_t oScol = oBsum + 4096;                         // E ints
    size_t oA    = oScol + (size_t)E * 4;                // N*64 floats (hW0s; later hW1s)
    size_t oB    = oA + (size_t)N * 256;                 // N*64 floats (scratch deg/cursor; later h0)
    size_t oP    = oB + (size_t)N * 256;                 // G*32 floats pooled
    size_t oCnt  = oP + (size_t)G * 128;                 // G ints

    float* invs   = (float*)(ws + oInvs);
    int*   off    = (int*)(ws + oOff);
    int*   bsum   = (int*)(ws + oBsum);
    int*   scol   = (int*)(ws + oScol);
    float* bufA   = (float*)(ws + oA);
    float* bufB   = (float*)(ws + oB);
    float* pooled = (float*)(ws + oP);
    int*   cnt    = (int*)(ws + oCnt);

    // deg and cursor live in bufB's space until aggregation overwrites it
    int* deg    = (int*)bufB;
    int* cursor = (int*)bufB + N;

    hipMemsetAsync(deg, 0, (size_t)N * 4, stream);
    hipMemsetAsync(pooled, 0, (size_t)G * 128 + (size_t)G * 4, stream);

    // degree + inv-sqrt
    k_deg<<<(E + 255) / 256, 256, 0, stream>>>(erow, deg, E);
    k_invsqrt<<<nb, 256, 0, stream>>>(deg, invs, N);

    // CSR build
    k_bsum<<<nb, 256, 0, stream>>>(deg, bsum, N);
    k_scan_bsums<<<1, 1024, 0, stream>>>(bsum, nb);
    k_scan_final<<<nb, 256, 0, stream>>>(deg, bsum, off, cursor, N, E);
    k_scatter<<<(E + 255) / 256, 256, 0, stream>>>(erow, ecol, cursor, scol, E);

    // layer 0: project (invs-scaled) then gather-aggregate
    k_gemm0<<<(N + 3) / 4, 256, 0, stream>>>(x, W0, invs, bufA, N);
    k_csr_agg64<<<N, 256, 0, stream>>>(scol, off, invs, bufA, b0, bufB, N);

    // layer 1: project then gather-aggregate fused with mean-pool
    k_gemm1<<<(N + 7) / 8, 256, 0, stream>>>(bufB, W1, invs, bufA, N);
    k_csr_agg32_pool<<<N, 256, 0, stream>>>(scol, off, invs, bufA, b1, gidx, pooled, N);
    k_cnt<<<nb, 256, 0, stream>>>(gidx, cnt, N);

    // dense head
    k_final<<<(G * 16 + 255) / 256, 256, 0, stream>>>(pooled, cnt, Wd, bd, out, G * 16);
}

// Round 3
// 734.209 us; speedup vs baseline: 2.0681x; 1.4204x over previous
//
#include <hip/hip_runtime.h>

#define BSHIFT 7
#define BSIZE 128          // nodes per bucket
#define MAXB 1024          // max buckets (N <= 131072); col must fit 17 bits
#define CHUNK 16384        // edges per block in bucket passes

// ---------------- bucketed CSR build ----------------

__global__ __launch_bounds__(256) void k_bhist(const int* __restrict__ row,
                                               int* __restrict__ bhist,
                                               int E, int nbuckets) {
    __shared__ int h[MAXB];
    for (int i = threadIdx.x; i < nbuckets; i += 256) h[i] = 0;
    __syncthreads();
    int start = blockIdx.x * CHUNK;
    int end = min(E, start + CHUNK);
    for (int i = start + threadIdx.x; i < end; i += 256)
        atomicAdd(&h[row[i] >> BSHIFT], 1);
    __syncthreads();
    for (int i = threadIdx.x; i < nbuckets; i += 256)
        if (h[i]) atomicAdd(&bhist[i], h[i]);
}

__global__ __launch_bounds__(1024) void k_bscan(const int* __restrict__ bhist,
                                                int* __restrict__ boff,
                                                int* __restrict__ bcur,
                                                int nbuckets, int E) {
    __shared__ int sd[1024];
    int t = threadIdx.x;
    int v = (t < nbuckets) ? bhist[t] : 0;
    sd[t] = v;
    __syncthreads();
    for (int d = 1; d < 1024; d <<= 1) {
        int a = (t >= d) ? sd[t - d] : 0;
        __syncthreads();
        sd[t] += a;
        __syncthreads();
    }
    if (t < nbuckets) { int ex = sd[t] - v; boff[t] = ex; bcur[t] = ex; }
    if (t == 0) boff[nbuckets] = E;
}

// scatter edges grouped by bucket; pack (localrow<<17 | col) into one int
__global__ __launch_bounds__(256) void k_bscatter(const int* __restrict__ row,
                                                  const int* __restrict__ col,
                                                  int* __restrict__ bcur,
                                                  int* __restrict__ bedge,
                                                  int E, int nbuckets) {
    __shared__ int h[MAXB];
    __shared__ int base[MAXB];
    for (int i = threadIdx.x; i < nbuckets; i += 256) h[i] = 0;
    __syncthreads();
    int start = blockIdx.x * CHUNK;
    int end = min(E, start + CHUNK);
    for (int i = start + threadIdx.x; i < end; i += 256)
        atomicAdd(&h[row[i] >> BSHIFT], 1);
    __syncthreads();
    for (int i = threadIdx.x; i < nbuckets; i += 256) {
        int c = h[i];
        base[i] = c ? atomicAdd(&bcur[i], c) : 0;
        h[i] = 0;
    }
    __syncthreads();
    for (int i = start + threadIdx.x; i < end; i += 256) {
        int r = row[i], c = col[i];
        int b = r >> BSHIFT;
        int p = base[b] + atomicAdd(&h[b], 1);
        bedge[p] = ((r & (BSIZE - 1)) << 17) | c;
    }
}

// block per bucket: bucket-grouped edges -> exact CSR (scol, off) + invs.
// All bookkeeping in LDS; scol writes confined to one ~16KB window per block.
__global__ __launch_bounds__(256) void k_bexact(const int* __restrict__ bedge,
                                                const int* __restrict__ boff,
                                                int* __restrict__ off,
                                                int* __restrict__ scol,
                                                float* __restrict__ invs,
                                                int N, int E) {
    __shared__ int ldeg[BSIZE];
    __shared__ int lex[BSIZE];
    int b = blockIdx.x;
    int tid = threadIdx.x;
    int nstart = b << BSHIFT;
    int ncount = min(BSIZE, N - nstart);
    int s = boff[b], e = boff[b + 1];
    if (tid < BSIZE) ldeg[tid] = 0;
    __syncthreads();
    for (int k = s + tid; k < e; k += 256)
        atomicAdd(&ldeg[bedge[k] >> 17], 1);
    __syncthreads();
    if (tid < BSIZE) lex[tid] = ldeg[tid];
    __syncthreads();
    for (int d = 1; d < BSIZE; d <<= 1) {
        int a = 0;
        if (tid < BSIZE && tid >= d) a = lex[tid - d];
        __syncthreads();
        if (tid < BSIZE) lex[tid] += a;
        __syncthreads();
    }
    if (tid < BSIZE) lex[tid] -= ldeg[tid];   // exclusive scan
    __syncthreads();
    if (tid < ncount) {
        int node = nstart + tid;
        off[node] = s + lex[tid];
        invs[node] = rsqrtf((float)(ldeg[tid] + 1));
    }
    if (b == 0 && tid == 0) off[N] = E;
    if (tid < BSIZE) ldeg[tid] = 0;           // reuse as per-node cursor
    __syncthreads();
    for (int k = s + tid; k < e; k += 256) {
        int p = bedge[k];
        int lr = p >> 17;
        int pos = s + lex[lr] + atomicAdd(&ldeg[lr], 1);
        scol[pos] = p & 0x1FFFF;
    }
}

// ---------------- projections (store invs[row]-scaled) ----------------

__global__ __launch_bounds__(256) void k_gemm0(const float* __restrict__ x,
                                               const float* __restrict__ W,
                                               const float* __restrict__ invs,
                                               float* __restrict__ out, int N) {
    __shared__ float sW[128 * 64];
    for (int i = threadIdx.x; i < 128 * 64; i += 256) sW[i] = W[i];
    __syncthreads();
    int row = blockIdx.x * 4 + (threadIdx.x >> 6);
    int c = threadIdx.x & 63;
    if (row >= N) return;
    const float4* xr = (const float4*)(x + (size_t)row * 128);
    float acc = 0.f;
#pragma unroll
    for (int k4 = 0; k4 < 32; ++k4) {
        float4 xv = xr[k4];
        int k = k4 * 4;
        acc = fmaf(xv.x, sW[(k + 0) * 64 + c], acc);
        acc = fmaf(xv.y, sW[(k + 1) * 64 + c], acc);
        acc = fmaf(xv.z, sW[(k + 2) * 64 + c], acc);
        acc = fmaf(xv.w, sW[(k + 3) * 64 + c], acc);
    }
    out[(size_t)row * 64 + c] = invs[row] * acc;
}

__global__ __launch_bounds__(256) void k_gemm1(const float* __restrict__ h,
                                               const float* __restrict__ W,
                                               const float* __restrict__ invs,
                                               float* __restrict__ out, int N) {
    __shared__ float sW[64 * 32];
    for (int i = threadIdx.x; i < 64 * 32; i += 256) sW[i] = W[i];
    __syncthreads();
    int row = blockIdx.x * 8 + (threadIdx.x >> 5);
    int c = threadIdx.x & 31;
    if (row >= N) return;
    const float4* hr = (const float4*)(h + (size_t)row * 64);
    float acc = 0.f;
#pragma unroll
    for (int k4 = 0; k4 < 16; ++k4) {
        float4 hv = hr[k4];
        int k = k4 * 4;
        acc = fmaf(hv.x, sW[(k + 0) * 32 + c], acc);
        acc = fmaf(hv.y, sW[(k + 1) * 32 + c], acc);
        acc = fmaf(hv.z, sW[(k + 2) * 32 + c], acc);
        acc = fmaf(hv.w, sW[(k + 3) * 32 + c], acc);
    }
    out[(size_t)row * 32 + c] = invs[row] * acc;
}

// ---------------- CSR gather-aggregate ----------------

__global__ __launch_bounds__(256) void k_csr_agg64(const int* __restrict__ scol,
                                                   const int* __restrict__ off,
                                                   const float* __restrict__ invs,
                                                   const float* __restrict__ hWs,
                                                   const float* __restrict__ bias,
                                                   float* __restrict__ h0, int N) {
    int i = blockIdx.x;
    int lane = threadIdx.x & 63, w = threadIdx.x >> 6;
    int s = off[i], e = off[i + 1];
    float a0 = 0.f, a1 = 0.f;
    int k = s + w;
    for (; k + 4 < e; k += 8) {
        int c0 = scol[k], c1 = scol[k + 4];
        a0 += hWs[(size_t)c0 * 64 + lane];
        a1 += hWs[(size_t)c1 * 64 + lane];
    }
    if (k < e) a0 += hWs[(size_t)scol[k] * 64 + lane];
    __shared__ float red[4][64];
    red[w][lane] = a0 + a1;
    __syncthreads();
    if (threadIdx.x < 64) {
        float v = red[0][lane] + red[1][lane] + red[2][lane] + red[3][lane];
        v = invs[i] * (v + hWs[(size_t)i * 64 + lane]) + bias[lane];
        h0[(size_t)i * 64 + lane] = v > 0.f ? v : 0.f;
    }
}

__global__ __launch_bounds__(256) void k_csr_agg32_pool(const int* __restrict__ scol,
                                                        const int* __restrict__ off,
                                                        const float* __restrict__ invs,
                                                        const float* __restrict__ hWs,
                                                        const float* __restrict__ bias,
                                                        const int* __restrict__ gidx,
                                                        float* __restrict__ pooled,
                                                        int N) {
    int i = blockIdx.x;
    int lane = threadIdx.x & 31, w = threadIdx.x >> 5;
    int s = off[i], e = off[i + 1];
    float a0 = 0.f, a1 = 0.f;
    int k = s + w;
    for (; k + 8 < e; k += 16) {
        int c0 = scol[k], c1 = scol[k + 8];
        a0 += hWs[(size_t)c0 * 32 + lane];
        a1 += hWs[(size_t)c1 * 32 + lane];
    }
    if (k < e) a0 += hWs[(size_t)scol[k] * 32 + lane];
    __shared__ float red[8][32];
    red[w][lane] = a0 + a1;
    __syncthreads();
    if (threadIdx.x < 32) {
        float v = 0.f;
#pragma unroll
        for (int q = 0; q < 8; ++q) v += red[q][lane];
        v = invs[i] * (v + hWs[(size_t)i * 32 + lane]) + bias[lane];
        v = v > 0.f ? v : 0.f;
        atomicAdd(&pooled[(size_t)gidx[i] * 32 + lane], v);
    }
}

__global__ __launch_bounds__(256) void k_cnt(const int* __restrict__ gidx,
                                             int* __restrict__ cnt, int N) {
    int i = blockIdx.x * 256 + threadIdx.x;
    if (i < N) atomicAdd(&cnt[gidx[i]], 1);
}

__global__ __launch_bounds__(256) void k_final(const float* __restrict__ pooled,
                                               const int* __restrict__ cnt,
                                               const float* __restrict__ Wd,
                                               const float* __restrict__ bd,
                                               float* __restrict__ out, int total) {
    int idx = blockIdx.x * 256 + threadIdx.x;
    if (idx >= total) return;
    int g = idx >> 4, c = idx & 15;
    float denom = fmaxf((float)cnt[g], 1.0f);
    float acc = 0.f;
#pragma unroll
    for (int j = 0; j < 32; ++j)
        acc = fmaf(pooled[g * 32 + j], Wd[j * 16 + c], acc);
    out[idx] = acc / denom + bd[c];
}

// ---------------- launch ----------------

extern "C" void kernel_launch(void* const* d_in, const int* in_sizes, int n_in,
                              void* d_out, int out_size, void* d_ws, size_t ws_size,
                              hipStream_t stream) {
    const float* x   = (const float*)d_in[0];
    const int*  erow = (const int*)d_in[1];              // edge targets
    const int*  gidx = (const int*)d_in[2];
    const float* W0  = (const float*)d_in[3];
    const float* b0  = (const float*)d_in[4];
    const float* W1  = (const float*)d_in[5];
    const float* b1  = (const float*)d_in[6];
    const float* Wd  = (const float*)d_in[7];
    const float* bd  = (const float*)d_in[8];
    float* out = (float*)d_out;

    const int E = in_sizes[1] / 2;
    const int* ecol = erow + E;                          // edge sources
    const int N = in_sizes[2];
    const int G = out_size / 16;
    const int nbuckets = (N + BSIZE - 1) / BSIZE;
    const int nchunks = (E + CHUNK - 1) / CHUNK;

    char* ws = (char*)d_ws;
    size_t oInvs = 0;                                    // N floats
    size_t oOff  = oInvs + (size_t)N * 4;                // (N+8) ints
    size_t oBh   = oOff + (size_t)(N + 8) * 4;           // MAXB ints
    size_t oBo   = oBh + (size_t)MAXB * 4;               // MAXB+8 ints
    size_t oBc   = oBo + (size_t)(MAXB + 8) * 4;         // MAXB ints
    size_t oScol = oBc + (size_t)MAXB * 4;               // E ints
    size_t oA    = oScol + (size_t)E * 4;                // N*64 floats
    size_t oB    = oA + (size_t)N * 256;                 // N*64 floats (bedge early, h0 later)
    size_t oP    = oB + (size_t)N * 256;                 // G*32 floats pooled
    size_t oCnt  = oP + (size_t)G * 128;                 // G ints

    float* invs   = (float*)(ws + oInvs);
    int*   off    = (int*)(ws + oOff);
    int*   bhist  = (int*)(ws + oBh);
    int*   boff   = (int*)(ws + oBo);
    int*   bcur   = (int*)(ws + oBc);
    int*   scol   = (int*)(ws + oScol);
    float* bufA   = (float*)(ws + oA);
    float* bufB   = (float*)(ws + oB);
    float* pooled = (float*)(ws + oP);
    int*   cnt    = (int*)(ws + oCnt);
    int*   bedge  = (int*)bufB;                          // dead before h0 is written

    hipMemsetAsync(bhist, 0, (size_t)MAXB * 4, stream);
    hipMemsetAsync(pooled, 0, (size_t)G * 128 + (size_t)G * 4, stream);

    // CSR build via two-level counting sort (also yields deg -> invs)
    k_bhist<<<nchunks, 256, 0, stream>>>(erow, bhist, E, nbuckets);
    k_bscan<<<1, 1024, 0, stream>>>(bhist, boff, bcur, nbuckets, E);
    k_bscatter<<<nchunks, 256, 0, stream>>>(erow, ecol, bcur, bedge, E, nbuckets);
    k_bexact<<<nbuckets, 256, 0, stream>>>(bedge, boff, off, scol, invs, N, E);

    // layer 0: project (invs-scaled) then gather-aggregate
    k_gemm0<<<(N + 3) / 4, 256, 0, stream>>>(x, W0, invs, bufA, N);
    k_csr_agg64<<<N, 256, 0, stream>>>(scol, off, invs, bufA, b0, bufB, N);

    // layer 1: project then gather-aggregate fused with mean-pool
    k_gemm1<<<(N + 7) / 8, 256, 0, stream>>>(bufB, W1, invs, bufA, N);
    k_csr_agg32_pool<<<N, 256, 0, stream>>>(scol, off, invs, bufA, b1, gidx, pooled, N);
    k_cnt<<<(N + 255) / 256, 256, 0, stream>>>(gidx, cnt, N);

    // dense head
    k_final<<<(G * 16 + 255) / 256, 256, 0, stream>>>(pooled, cnt, Wd, bd, out, G * 16);
}